// Round 7
// baseline (473.578 us; speedup 1.0000x reference)
//
#include <hip/hip_runtime.h>

// Inputs are f32 (verified R2-R6). bf16 staging internally; f32 accumulate; f32 out.

// ---------- bf16 bit helpers ----------
__device__ __forceinline__ float b2f(unsigned short s) {
    union { unsigned int u; float f; } c; c.u = ((unsigned int)s) << 16; return c.f;
}
__device__ __forceinline__ unsigned short f2b(float f) {
    union { float f; unsigned int u; } c; c.f = f;
    unsigned int u = c.u;
    unsigned int r = u + 0x7FFFu + ((u >> 16) & 1u);   // RNE
    return (unsigned short)(r >> 16);
}
__device__ __forceinline__ unsigned int pack2(float lo, float hi) {
    return ((unsigned int)f2b(hi) << 16) | f2b(lo);
}
__device__ __forceinline__ void fma8(float* a, float v, uint4 w) {
    a[0] = fmaf(v, b2f((unsigned short)w.x), a[0]);
    a[1] = fmaf(v, b2f((unsigned short)(w.x >> 16)), a[1]);
    a[2] = fmaf(v, b2f((unsigned short)w.y), a[2]);
    a[3] = fmaf(v, b2f((unsigned short)(w.y >> 16)), a[3]);
    a[4] = fmaf(v, b2f((unsigned short)w.z), a[4]);
    a[5] = fmaf(v, b2f((unsigned short)(w.z >> 16)), a[5]);
    a[6] = fmaf(v, b2f((unsigned short)w.w), a[6]);
    a[7] = fmaf(v, b2f((unsigned short)(w.w >> 16)), a[7]);
}

typedef __attribute__((ext_vector_type(8))) short bf16x8;
typedef __attribute__((ext_vector_type(4))) float f32x4;

#define T_TILES 10

// ---------- K1: fused prep: rowptr | W1 -> bf16 | x/x_tilde -> interleaved bf16 ----------
// xint layout: node row = 512 B: [x 128 bf16][x_tilde 128 bf16]
// conv part: one thread handles the SAME 8-dim slot of BOTH matrices -> full-density writes
__global__ __launch_bounds__(256) void prep(
    const int* __restrict__ row, int* __restrict__ rp, int n, int e, int rb,
    const float* __restrict__ w1, unsigned short* __restrict__ w1b, int pb,
    const float* __restrict__ x, const float* __restrict__ xt,
    unsigned short* __restrict__ xint, int total8)
{
    int b = blockIdx.x, tid = threadIdx.x;
    if (b < rb) {                                   // --- build row_ptr ---
        int i = b * 256 + tid;
        if (i > e) return;
        if (i == 0) {
            int r1 = row[0];
            for (int rr = 0; rr <= r1; ++rr) rp[rr] = 0;
        } else if (i == e) {
            int r0 = row[e - 1];
            for (int rr = r0 + 1; rr <= n; ++rr) rp[rr] = e;
        } else {
            int r0 = row[i - 1], r1 = row[i];
            for (int rr = r0 + 1; rr <= r1; ++rr) rp[rr] = i;
        }
    } else if (b < rb + pb) {                       // --- W1 -> bf16 ---
        int i = (b - rb) * 256 + tid;               // 0..32767
        if (i < 32768) w1b[i] = f2b(w1[i]);
    } else {                                        // --- x & xt conversion (interleaved) ---
        int i = (b - rb - pb) * 256 + tid;          // 8-elem slot index
        if (i >= total8) return;
        int node = i >> 4, sub = i & 15;
        const float4* px = (const float4*)x + (size_t)i * 2;
        const float4* pt = (const float4*)xt + (size_t)i * 2;
        float4 a0 = px[0], a1 = px[1];
        float4 b0 = pt[0], b1 = pt[1];
        uint4 ox, ot;
        ox.x = pack2(a0.x, a0.y); ox.y = pack2(a0.z, a0.w);
        ox.z = pack2(a1.x, a1.y); ox.w = pack2(a1.z, a1.w);
        ot.x = pack2(b0.x, b0.y); ot.y = pack2(b0.z, b0.w);
        ot.z = pack2(b1.x, b1.y); ot.w = pack2(b1.z, b1.w);
        unsigned short* base = xint + (size_t)node * 256 + sub * 8;
        *(uint4*)(base)       = ox;
        *(uint4*)(base + 128) = ot;
    }
}

// ---------- K2: dual SpMM; col/vals preloaded per 64-edge chunk, 16 edges/iter ----------
// lane = g*16 + l: group g handles edges {base+4u+g}, lane l handles dims [8l,8l+8)
__global__ __launch_bounds__(256) void spmm_dual4(
    const unsigned short* __restrict__ xint, const float* __restrict__ vals,
    const int* __restrict__ col, const int* __restrict__ row_ptr,
    unsigned short* __restrict__ aggx, unsigned short* __restrict__ aggt, int n)
{
    int wave = threadIdx.x >> 6;
    int lane = threadIdx.x & 63;
    int g = lane >> 4, l = lane & 15;
    int r = blockIdx.x * 4 + wave;
    if (r >= n) return;
    int e0 = row_ptr[r], e1 = row_ptr[r + 1];
    float ax[8], at[8];
#pragma unroll
    for (int d = 0; d < 8; ++d) { ax[d] = 0.f; at[d] = 0.f; }
    for (int chunk = e0; chunk < e1; chunk += 64) {
        int m = e1 - chunk; if (m > 64) m = 64;     // edges in this chunk
        int ce = chunk + (lane < m ? lane : m - 1); // coalesced preload (clamped)
        int cc = col[ce];
        float cv = (lane < m) ? vals[ce] : 0.f;
        for (int base = 0; base < m; base += 16) {
            uint4 xw[4], tw[4];
            float fv[4];
#pragma unroll
            for (int u = 0; u < 4; ++u) {
                int idx = base + 4 * u + g;
                int idc = idx < m ? idx : m - 1;    // clamp: duplicate line is cache-hot
                int c  = __shfl(cc, idc, 64);
                float v = __shfl(cv, idc, 64);
                fv[u] = (idx < m) ? v : 0.f;
                const uint4* p = (const uint4*)(xint + (size_t)c * 256);
                xw[u] = p[l];
                tw[u] = p[16 + l];
            }
#pragma unroll
            for (int u = 0; u < 4; ++u) { fma8(ax, fv[u], xw[u]); fma8(at, fv[u], tw[u]); }
        }
    }
#pragma unroll
    for (int d = 0; d < 8; ++d) {
        ax[d] += __shfl_xor(ax[d], 16, 64);
        ax[d] += __shfl_xor(ax[d], 32, 64);
        at[d] += __shfl_xor(at[d], 16, 64);
        at[d] += __shfl_xor(at[d], 32, 64);
    }
    if (g == 0) {
        uint4 o;
        o.x = pack2(ax[0], ax[1]); o.y = pack2(ax[2], ax[3]);
        o.z = pack2(ax[4], ax[5]); o.w = pack2(ax[6], ax[7]);
        ((uint4*)(aggx + (size_t)r * 128))[l] = o;
    } else if (g == 1) {
        uint4 o;
        o.x = pack2(at[0], at[1]); o.y = pack2(at[2], at[3]);
        o.z = pack2(at[4], at[5]); o.w = pack2(at[6], at[7]);
        ((uint4*)(aggt + (size_t)r * 128))[l] = o;
    }
}

// ---------- K3: GEMM + colsum; W1 resident; atomic-free partials [block][dim] ----------
// C/D layout: col = nl, row = quad*4 + r. Column sum => sum over r, then quad bits.
__global__ __launch_bounds__(256) void gemm_colsum3(
    const short* __restrict__ aggb, const short* __restrict__ w1,
    const float* __restrict__ pa, float* __restrict__ partial, int ntiles)
{
    int tid = threadIdx.x;
    int w = tid >> 6, lane = tid & 63;
    int nl = lane & 15, quad = lane >> 4;
    const short* brow = w1 + ((size_t)(4 * w) * 16 + nl) * 128 + quad * 8;
    bf16x8 bf[4][4];
#pragma unroll
    for (int j = 0; j < 4; ++j)
#pragma unroll
        for (int k = 0; k < 4; ++k)
            bf[j][k] = *(const bf16x8*)(brow + j * 2048 + k * 32);
    float aslope = pa[0];
    float cs[4] = {0.f, 0.f, 0.f, 0.f};
    int t0 = blockIdx.x * T_TILES;
    int nt = ntiles - t0; if (nt > T_TILES) nt = T_TILES;
    for (int i = 0; i < nt; ++i) {
        const short* arow = aggb + ((size_t)(t0 + i) * 16 + nl) * 128 + quad * 8;
        bf16x8 af[4];
#pragma unroll
        for (int k = 0; k < 4; ++k) af[k] = *(const bf16x8*)(arow + k * 32);
        f32x4 acc[4];
#pragma unroll
        for (int j = 0; j < 4; ++j) acc[j] = (f32x4){0.f, 0.f, 0.f, 0.f};
#pragma unroll
        for (int k = 0; k < 4; ++k)
#pragma unroll
            for (int j = 0; j < 4; ++j)
                acc[j] = __builtin_amdgcn_mfma_f32_16x16x32_bf16(af[k], bf[j][k], acc[j], 0, 0, 0);
#pragma unroll
        for (int j = 0; j < 4; ++j)
#pragma unroll
            for (int r = 0; r < 4; ++r) {
                float z = acc[j][r];
                cs[j] += (z >= 0.f) ? z : aslope * z;
            }
    }
#pragma unroll
    for (int j = 0; j < 4; ++j) {
        cs[j] += __shfl_xor(cs[j], 16, 64);   // reduce rows: quad bits only
        cs[j] += __shfl_xor(cs[j], 32, 64);
    }
    if (quad == 0)
#pragma unroll
        for (int j = 0; j < 4; ++j)
            partial[(size_t)blockIdx.x * 256 + (4 * w + j) * 16 + nl] = cs[j];
}

// ---------- K4: finalize: reduce partials -> sigmoid -> v = w_bil @ s (one block) ----------
__global__ __launch_bounds__(256) void finalize(
    const float* __restrict__ partial, int nb, const float* __restrict__ wbil,
    float* __restrict__ v, float invN)
{
    __shared__ float s_lds[256];
    int t = threadIdx.x;
    float s = 0.f;
    for (int b = 0; b < nb; ++b)              // coalesced: lanes read adjacent dims
        s += partial[(size_t)b * 256 + t];
    s_lds[t] = 1.f / (1.f + expf(-s * invN));
    __syncthreads();
    const float* wrow = wbil + (size_t)t * 256;
    float acc = 0.f;
#pragma unroll 8
    for (int j = 0; j < 256; ++j)
        acc = fmaf(wrow[j], s_lds[j], acc);
    v[t] = acc;
}

// ---------- K5: GEMM + dot with v; W1 resident; LDS cross-wave reduce ----------
__global__ __launch_bounds__(256) void gemm_dp2(
    const short* __restrict__ aggx, const short* __restrict__ aggt,
    const short* __restrict__ w1, const float* __restrict__ pa,
    const float* __restrict__ v, float* __restrict__ out, int ntiles, int N)
{
    __shared__ float dpbuf[4][T_TILES * 16];
    int tid = threadIdx.x;
    int w = tid >> 6, lane = tid & 63;
    int nl = lane & 15, quad = lane >> 4;
    const short* agg = blockIdx.y ? aggt : aggx;
    const short* brow = w1 + ((size_t)(4 * w) * 16 + nl) * 128 + quad * 8;
    bf16x8 bf[4][4];
#pragma unroll
    for (int j = 0; j < 4; ++j)
#pragma unroll
        for (int k = 0; k < 4; ++k)
            bf[j][k] = *(const bf16x8*)(brow + j * 2048 + k * 32);
    float vreg[4];
#pragma unroll
    for (int j = 0; j < 4; ++j) vreg[j] = v[(4 * w + j) * 16 + nl];
    float aslope = pa[0];
    int t0 = blockIdx.x * T_TILES;
    int nt = ntiles - t0; if (nt > T_TILES) nt = T_TILES;
    for (int i = 0; i < nt; ++i) {
        const short* arow = agg + ((size_t)(t0 + i) * 16 + nl) * 128 + quad * 8;
        bf16x8 af[4];
#pragma unroll
        for (int k = 0; k < 4; ++k) af[k] = *(const bf16x8*)(arow + k * 32);
        f32x4 acc[4];
#pragma unroll
        for (int j = 0; j < 4; ++j) acc[j] = (f32x4){0.f, 0.f, 0.f, 0.f};
#pragma unroll
        for (int k = 0; k < 4; ++k)
#pragma unroll
            for (int j = 0; j < 4; ++j)
                acc[j] = __builtin_amdgcn_mfma_f32_16x16x32_bf16(af[k], bf[j][k], acc[j], 0, 0, 0);
        float p[4] = {0.f, 0.f, 0.f, 0.f};
#pragma unroll
        for (int j = 0; j < 4; ++j)
#pragma unroll
            for (int r = 0; r < 4; ++r) {
                float z = acc[j][r];
                float h = (z >= 0.f) ? z : aslope * z;
                p[r] = fmaf(h, vreg[j], p[r]);
            }
#pragma unroll
        for (int r = 0; r < 4; ++r) {   // reduce over nl bits (16 cols of the slice)
            p[r] += __shfl_xor(p[r], 1, 64);
            p[r] += __shfl_xor(p[r], 2, 64);
            p[r] += __shfl_xor(p[r], 4, 64);
            p[r] += __shfl_xor(p[r], 8, 64);
        }
        if (nl == 0)
#pragma unroll
            for (int r = 0; r < 4; ++r)
                dpbuf[w][i * 16 + quad * 4 + r] = p[r];
    }
    __syncthreads();
    int nloc = nt * 16;
    for (int idx = tid; idx < nloc; idx += 256) {
        float s = dpbuf[0][idx] + dpbuf[1][idx] + dpbuf[2][idx] + dpbuf[3][idx];
        out[(size_t)blockIdx.y * N + (size_t)t0 * 16 + idx] = s;
    }
}

extern "C" void kernel_launch(void* const* d_in, const int* in_sizes, int n_in,
                              void* d_out, int out_size, void* d_ws, size_t ws_size,
                              hipStream_t stream) {
    const float* x    = (const float*)d_in[0];
    const float* xt   = (const float*)d_in[1];
    const float* vals = (const float*)d_in[2];
    const int* row    = (const int*)d_in[3];
    const int* col    = (const int*)d_in[4];
    const float* w1   = (const float*)d_in[5];
    const float* pa   = (const float*)d_in[6];
    const float* wb   = (const float*)d_in[7];

    const int N = in_sizes[0] / 128;
    const int E = in_sizes[2];
    const int ntiles = (N + 15) / 16;
    const int cs_blocks = (ntiles + T_TILES - 1) / T_TILES;

    char* ws = (char*)d_ws;
    size_t off = 0;
    auto alloc = [&](size_t bytes) { char* p = ws + off; off = (off + bytes + 255) & ~(size_t)255; return p; };
    int* row_ptr         = (int*)alloc((size_t)(N + 1) * 4);
    unsigned short* aggx = (unsigned short*)alloc((size_t)N * 128 * 2);
    unsigned short* aggt = (unsigned short*)alloc((size_t)N * 128 * 2);
    unsigned short* w1b  = (unsigned short*)alloc(32768 * 2);
    float* partial       = (float*)alloc((size_t)cs_blocks * 256 * 4);
    float* vvec          = (float*)alloc(256 * 4);
    unsigned short* xint = (unsigned short*)alloc((size_t)N * 256 * 2);  // x|xt interleaved bf16

    int rb = (E + 1 + 255) / 256;
    int pb = 128;
    int total8 = (N * 128) / 8;
    int cvb = (total8 + 255) / 256;
    prep<<<rb + pb + cvb, 256, 0, stream>>>(
        row, row_ptr, N, E, rb, w1, w1b, pb, x, xt, xint, total8);

    spmm_dual4<<<(N + 3) / 4, 256, 0, stream>>>(xint, vals, col, row_ptr, aggx, aggt, N);

    gemm_colsum3<<<cs_blocks, 256, 0, stream>>>(
        (const short*)aggx, (const short*)w1b, pa, partial, ntiles);
    finalize<<<1, 256, 0, stream>>>(partial, cs_blocks, wb, vvec, 1.0f / (float)N);
    gemm_dp2<<<dim3(cs_blocks, 2), 256, 0, stream>>>(
        (const short*)aggx, (const short*)aggt, (const short*)w1b, pa, vvec,
        (float*)d_out, ntiles, N);
}

// Round 8
// 336.787 us; speedup vs baseline: 1.4062x; 1.4062x over previous
//
#include <hip/hip_runtime.h>

// Inputs are f32 (verified R2-R6). bf16 staging internally; f32 accumulate; f32 out.

// ---------- bf16 bit helpers ----------
__device__ __forceinline__ float b2f(unsigned short s) {
    union { unsigned int u; float f; } c; c.u = ((unsigned int)s) << 16; return c.f;
}
__device__ __forceinline__ unsigned short f2b(float f) {
    union { float f; unsigned int u; } c; c.f = f;
    unsigned int u = c.u;
    unsigned int r = u + 0x7FFFu + ((u >> 16) & 1u);   // RNE
    return (unsigned short)(r >> 16);
}
__device__ __forceinline__ unsigned int pack2(float lo, float hi) {
    return ((unsigned int)f2b(hi) << 16) | f2b(lo);
}
__device__ __forceinline__ void fma8(float* a, float v, uint4 w) {
    a[0] = fmaf(v, b2f((unsigned short)w.x), a[0]);
    a[1] = fmaf(v, b2f((unsigned short)(w.x >> 16)), a[1]);
    a[2] = fmaf(v, b2f((unsigned short)w.y), a[2]);
    a[3] = fmaf(v, b2f((unsigned short)(w.y >> 16)), a[3]);
    a[4] = fmaf(v, b2f((unsigned short)w.z), a[4]);
    a[5] = fmaf(v, b2f((unsigned short)(w.z >> 16)), a[5]);
    a[6] = fmaf(v, b2f((unsigned short)w.w), a[6]);
    a[7] = fmaf(v, b2f((unsigned short)(w.w >> 16)), a[7]);
}

typedef __attribute__((ext_vector_type(8))) short bf16x8;
typedef __attribute__((ext_vector_type(4))) float f32x4;

#define T_TILES 10

// ---------- K1: fused prep: rowptr | W1 -> bf16 | x/x_tilde -> interleaved bf16 ----------
// xint layout: node row = 512 B: [x 128 bf16][x_tilde 128 bf16]
// conv part: one thread handles the SAME 8-dim slot of BOTH matrices -> full-density writes
__global__ __launch_bounds__(256) void prep(
    const int* __restrict__ row, int* __restrict__ rp, int n, int e, int rb,
    const float* __restrict__ w1, unsigned short* __restrict__ w1b, int pb,
    const float* __restrict__ x, const float* __restrict__ xt,
    unsigned short* __restrict__ xint, int total8)
{
    int b = blockIdx.x, tid = threadIdx.x;
    if (b < rb) {                                   // --- build row_ptr ---
        int i = b * 256 + tid;
        if (i > e) return;
        if (i == 0) {
            int r1 = row[0];
            for (int rr = 0; rr <= r1; ++rr) rp[rr] = 0;
        } else if (i == e) {
            int r0 = row[e - 1];
            for (int rr = r0 + 1; rr <= n; ++rr) rp[rr] = e;
        } else {
            int r0 = row[i - 1], r1 = row[i];
            for (int rr = r0 + 1; rr <= r1; ++rr) rp[rr] = i;
        }
    } else if (b < rb + pb) {                       // --- W1 -> bf16 ---
        int i = (b - rb) * 256 + tid;               // 0..32767
        if (i < 32768) w1b[i] = f2b(w1[i]);
    } else {                                        // --- x & xt conversion (interleaved) ---
        int i = (b - rb - pb) * 256 + tid;          // 8-elem slot index
        if (i >= total8) return;
        int node = i >> 4, sub = i & 15;
        const float4* px = (const float4*)x + (size_t)i * 2;
        const float4* pt = (const float4*)xt + (size_t)i * 2;
        float4 a0 = px[0], a1 = px[1];
        float4 b0 = pt[0], b1 = pt[1];
        uint4 ox, ot;
        ox.x = pack2(a0.x, a0.y); ox.y = pack2(a0.z, a0.w);
        ox.z = pack2(a1.x, a1.y); ox.w = pack2(a1.z, a1.w);
        ot.x = pack2(b0.x, b0.y); ot.y = pack2(b0.z, b0.w);
        ot.z = pack2(b1.x, b1.y); ot.w = pack2(b1.z, b1.w);
        unsigned short* base = xint + (size_t)node * 256 + sub * 8;
        *(uint4*)(base)       = ox;
        *(uint4*)(base + 128) = ot;
    }
}

// ---------- K2: dual SpMM; col/vals preloaded per 64-edge chunk, 16 edges/iter ----------
// lane = g*16 + l: group g handles edges {base+4u+g}, lane l handles dims [8l,8l+8)
__global__ __launch_bounds__(256) void spmm_dual4(
    const unsigned short* __restrict__ xint, const float* __restrict__ vals,
    const int* __restrict__ col, const int* __restrict__ row_ptr,
    unsigned short* __restrict__ aggx, unsigned short* __restrict__ aggt, int n)
{
    int wave = threadIdx.x >> 6;
    int lane = threadIdx.x & 63;
    int g = lane >> 4, l = lane & 15;
    int r = blockIdx.x * 4 + wave;
    if (r >= n) return;
    int e0 = row_ptr[r], e1 = row_ptr[r + 1];
    float ax[8], at[8];
#pragma unroll
    for (int d = 0; d < 8; ++d) { ax[d] = 0.f; at[d] = 0.f; }
    for (int chunk = e0; chunk < e1; chunk += 64) {
        int m = e1 - chunk; if (m > 64) m = 64;     // edges in this chunk
        int ce = chunk + (lane < m ? lane : m - 1); // coalesced preload (clamped)
        int cc = col[ce];
        float cv = (lane < m) ? vals[ce] : 0.f;
        for (int base = 0; base < m; base += 16) {
            uint4 xw[4], tw[4];
            float fv[4];
#pragma unroll
            for (int u = 0; u < 4; ++u) {
                int idx = base + 4 * u + g;
                int idc = idx < m ? idx : m - 1;    // clamp: duplicate line is cache-hot
                int c  = __shfl(cc, idc, 64);
                float v = __shfl(cv, idc, 64);
                fv[u] = (idx < m) ? v : 0.f;
                const uint4* p = (const uint4*)(xint + (size_t)c * 256);
                xw[u] = p[l];
                tw[u] = p[16 + l];
            }
#pragma unroll
            for (int u = 0; u < 4; ++u) { fma8(ax, fv[u], xw[u]); fma8(at, fv[u], tw[u]); }
        }
    }
#pragma unroll
    for (int d = 0; d < 8; ++d) {
        ax[d] += __shfl_xor(ax[d], 16, 64);
        ax[d] += __shfl_xor(ax[d], 32, 64);
        at[d] += __shfl_xor(at[d], 16, 64);
        at[d] += __shfl_xor(at[d], 32, 64);
    }
    if (g == 0) {
        uint4 o;
        o.x = pack2(ax[0], ax[1]); o.y = pack2(ax[2], ax[3]);
        o.z = pack2(ax[4], ax[5]); o.w = pack2(ax[6], ax[7]);
        ((uint4*)(aggx + (size_t)r * 128))[l] = o;
    } else if (g == 1) {
        uint4 o;
        o.x = pack2(at[0], at[1]); o.y = pack2(at[2], at[3]);
        o.z = pack2(at[4], at[5]); o.w = pack2(at[6], at[7]);
        ((uint4*)(aggt + (size_t)r * 128))[l] = o;
    }
}

// ---------- K3: GEMM + colsum; W1 resident; transposed atomic-free partials ----------
// C/D layout: col = nl, row = quad*4 + r. Column sum => sum over r, then quad bits.
// partial layout: [out_dim 256][block nb]  (coalesced for the parallel reducer)
__global__ __launch_bounds__(256) void gemm_colsum3(
    const short* __restrict__ aggb, const short* __restrict__ w1,
    const float* __restrict__ pa, float* __restrict__ partial, int ntiles, int nb)
{
    int tid = threadIdx.x;
    int w = tid >> 6, lane = tid & 63;
    int nl = lane & 15, quad = lane >> 4;
    const short* brow = w1 + ((size_t)(4 * w) * 16 + nl) * 128 + quad * 8;
    bf16x8 bf[4][4];
#pragma unroll
    for (int j = 0; j < 4; ++j)
#pragma unroll
        for (int k = 0; k < 4; ++k)
            bf[j][k] = *(const bf16x8*)(brow + j * 2048 + k * 32);
    float aslope = pa[0];
    float cs[4] = {0.f, 0.f, 0.f, 0.f};
    int t0 = blockIdx.x * T_TILES;
    int nt = ntiles - t0; if (nt > T_TILES) nt = T_TILES;
    for (int i = 0; i < nt; ++i) {
        const short* arow = aggb + ((size_t)(t0 + i) * 16 + nl) * 128 + quad * 8;
        bf16x8 af[4];
#pragma unroll
        for (int k = 0; k < 4; ++k) af[k] = *(const bf16x8*)(arow + k * 32);
        f32x4 acc[4];
#pragma unroll
        for (int j = 0; j < 4; ++j) acc[j] = (f32x4){0.f, 0.f, 0.f, 0.f};
#pragma unroll
        for (int k = 0; k < 4; ++k)
#pragma unroll
            for (int j = 0; j < 4; ++j)
                acc[j] = __builtin_amdgcn_mfma_f32_16x16x32_bf16(af[k], bf[j][k], acc[j], 0, 0, 0);
#pragma unroll
        for (int j = 0; j < 4; ++j)
#pragma unroll
            for (int r = 0; r < 4; ++r) {
                float z = acc[j][r];
                cs[j] += (z >= 0.f) ? z : aslope * z;
            }
    }
#pragma unroll
    for (int j = 0; j < 4; ++j) {
        cs[j] += __shfl_xor(cs[j], 16, 64);   // reduce rows: quad bits only
        cs[j] += __shfl_xor(cs[j], 32, 64);
    }
    if (quad == 0)
#pragma unroll
        for (int j = 0; j < 4; ++j)
            partial[(size_t)((4 * w + j) * 16 + nl) * nb + blockIdx.x] = cs[j];
}

// ---------- K4: parallel reduce + sigmoid -> s (one block per out dim) ----------
__global__ __launch_bounds__(256) void reduce_sig(
    const float* __restrict__ partial, int nb, float* __restrict__ s_out, float invN)
{
    __shared__ float l[256];
    int d = blockIdx.x, tid = threadIdx.x;
    float s = 0.f;
    for (int i = tid; i < nb; i += 256)       // coalesced contiguous run per block
        s += partial[(size_t)d * nb + i];
    l[tid] = s;
    __syncthreads();
    for (int o = 128; o > 0; o >>= 1) {
        if (tid < o) l[tid] += l[tid + o];
        __syncthreads();
    }
    if (tid == 0) s_out[d] = 1.f / (1.f + expf(-l[0] * invN));
}

// ---------- K5: v = w_bil @ s (single block) ----------
__global__ __launch_bounds__(256) void compute_v(
    const float* __restrict__ s_in, const float* __restrict__ wbil,
    float* __restrict__ v)
{
    __shared__ float s_lds[256];
    int t = threadIdx.x;
    s_lds[t] = s_in[t];
    __syncthreads();
    const float* wrow = wbil + (size_t)t * 256;
    float acc = 0.f;
#pragma unroll 8
    for (int j = 0; j < 256; ++j)
        acc = fmaf(wrow[j], s_lds[j], acc);
    v[t] = acc;
}

// ---------- K6: GEMM + dot with v; W1 resident; LDS cross-wave reduce ----------
__global__ __launch_bounds__(256) void gemm_dp2(
    const short* __restrict__ aggx, const short* __restrict__ aggt,
    const short* __restrict__ w1, const float* __restrict__ pa,
    const float* __restrict__ v, float* __restrict__ out, int ntiles, int N)
{
    __shared__ float dpbuf[4][T_TILES * 16];
    int tid = threadIdx.x;
    int w = tid >> 6, lane = tid & 63;
    int nl = lane & 15, quad = lane >> 4;
    const short* agg = blockIdx.y ? aggt : aggx;
    const short* brow = w1 + ((size_t)(4 * w) * 16 + nl) * 128 + quad * 8;
    bf16x8 bf[4][4];
#pragma unroll
    for (int j = 0; j < 4; ++j)
#pragma unroll
        for (int k = 0; k < 4; ++k)
            bf[j][k] = *(const bf16x8*)(brow + j * 2048 + k * 32);
    float vreg[4];
#pragma unroll
    for (int j = 0; j < 4; ++j) vreg[j] = v[(4 * w + j) * 16 + nl];
    float aslope = pa[0];
    int t0 = blockIdx.x * T_TILES;
    int nt = ntiles - t0; if (nt > T_TILES) nt = T_TILES;
    for (int i = 0; i < nt; ++i) {
        const short* arow = agg + ((size_t)(t0 + i) * 16 + nl) * 128 + quad * 8;
        bf16x8 af[4];
#pragma unroll
        for (int k = 0; k < 4; ++k) af[k] = *(const bf16x8*)(arow + k * 32);
        f32x4 acc[4];
#pragma unroll
        for (int j = 0; j < 4; ++j) acc[j] = (f32x4){0.f, 0.f, 0.f, 0.f};
#pragma unroll
        for (int k = 0; k < 4; ++k)
#pragma unroll
            for (int j = 0; j < 4; ++j)
                acc[j] = __builtin_amdgcn_mfma_f32_16x16x32_bf16(af[k], bf[j][k], acc[j], 0, 0, 0);
        float p[4] = {0.f, 0.f, 0.f, 0.f};
#pragma unroll
        for (int j = 0; j < 4; ++j)
#pragma unroll
            for (int r = 0; r < 4; ++r) {
                float z = acc[j][r];
                float h = (z >= 0.f) ? z : aslope * z;
                p[r] = fmaf(h, vreg[j], p[r]);
            }
#pragma unroll
        for (int r = 0; r < 4; ++r) {   // reduce over nl bits (16 cols of the slice)
            p[r] += __shfl_xor(p[r], 1, 64);
            p[r] += __shfl_xor(p[r], 2, 64);
            p[r] += __shfl_xor(p[r], 4, 64);
            p[r] += __shfl_xor(p[r], 8, 64);
        }
        if (nl == 0)
#pragma unroll
            for (int r = 0; r < 4; ++r)
                dpbuf[w][i * 16 + quad * 4 + r] = p[r];
    }
    __syncthreads();
    int nloc = nt * 16;
    for (int idx = tid; idx < nloc; idx += 256) {
        float s = dpbuf[0][idx] + dpbuf[1][idx] + dpbuf[2][idx] + dpbuf[3][idx];
        out[(size_t)blockIdx.y * N + (size_t)t0 * 16 + idx] = s;
    }
}

extern "C" void kernel_launch(void* const* d_in, const int* in_sizes, int n_in,
                              void* d_out, int out_size, void* d_ws, size_t ws_size,
                              hipStream_t stream) {
    const float* x    = (const float*)d_in[0];
    const float* xt   = (const float*)d_in[1];
    const float* vals = (const float*)d_in[2];
    const int* row    = (const int*)d_in[3];
    const int* col    = (const int*)d_in[4];
    const float* w1   = (const float*)d_in[5];
    const float* pa   = (const float*)d_in[6];
    const float* wb   = (const float*)d_in[7];

    const int N = in_sizes[0] / 128;
    const int E = in_sizes[2];
    const int ntiles = (N + 15) / 16;
    const int cs_blocks = (ntiles + T_TILES - 1) / T_TILES;

    char* ws = (char*)d_ws;
    size_t off = 0;
    auto alloc = [&](size_t bytes) { char* p = ws + off; off = (off + bytes + 255) & ~(size_t)255; return p; };
    int* row_ptr         = (int*)alloc((size_t)(N + 1) * 4);
    unsigned short* aggx = (unsigned short*)alloc((size_t)N * 128 * 2);
    unsigned short* aggt = (unsigned short*)alloc((size_t)N * 128 * 2);
    unsigned short* w1b  = (unsigned short*)alloc(32768 * 2);
    float* partial       = (float*)alloc((size_t)cs_blocks * 256 * 4);
    float* svec          = (float*)alloc(256 * 4);
    float* vvec          = (float*)alloc(256 * 4);
    unsigned short* xint = (unsigned short*)alloc((size_t)N * 256 * 2);  // x|xt interleaved bf16

    int rb = (E + 1 + 255) / 256;
    int pb = 128;
    int total8 = (N * 128) / 8;
    int cvb = (total8 + 255) / 256;
    prep<<<rb + pb + cvb, 256, 0, stream>>>(
        row, row_ptr, N, E, rb, w1, w1b, pb, x, xt, xint, total8);

    spmm_dual4<<<(N + 3) / 4, 256, 0, stream>>>(xint, vals, col, row_ptr, aggx, aggt, N);

    gemm_colsum3<<<cs_blocks, 256, 0, stream>>>(
        (const short*)aggx, (const short*)w1b, pa, partial, ntiles, cs_blocks);
    reduce_sig<<<256, 256, 0, stream>>>(partial, cs_blocks, svec, 1.0f / (float)N);
    compute_v<<<1, 256, 0, stream>>>(svec, wb, vvec);
    gemm_dp2<<<dim3(cs_blocks, 2), 256, 0, stream>>>(
        (const short*)aggx, (const short*)aggt, (const short*)w1b, pa, vvec,
        (float*)d_out, ntiles, N);
}